// Round 9
// baseline (441.006 us; speedup 1.0000x reference)
//
#include <hip/hip_runtime.h>
#include <math.h>
#include <stddef.h>

#define L9   9
#define NB   2
#define CF   1024
#define HW   400     // 20*20
#define CH   256
#define TEMPF 20.0f
#define EPSF  1e-12f

typedef _Float16 half8 __attribute__((ext_vector_type(8)));
typedef float f32x4 __attribute__((ext_vector_type(4)));
typedef unsigned short ushort_t;

// ---------------------------------------------------------------------------
// Kernel 1 (v2): sums of squares over C, vectorized float4 along ij.
// ---------------------------------------------------------------------------
__global__ __launch_bounds__(256) void norm_partial2(const float* __restrict__ fq,
                                                     const float* __restrict__ fs,
                                                     float* __restrict__ partial2) {
    int chunk = blockIdx.x, lb = blockIdx.y, t = blockIdx.z;
    int tid = threadIdx.x;
    if (tid >= 200) return;
    int half = tid / 100, p4 = tid - half * 100;
    const float* src = (t == 0 ? fq : fs) + (size_t)lb * CF * HW + p4 * 4;
    int c0 = chunk * 64 + half;
    f32x4 acc = {};
    #pragma unroll 8
    for (int it = 0; it < 32; ++it) {
        const float4 v = *(const float4*)(src + (size_t)(c0 + it * 2) * HW);
        acc[0] = fmaf(v.x, v.x, acc[0]);
        acc[1] = fmaf(v.y, v.y, acc[1]);
        acc[2] = fmaf(v.z, v.z, acc[2]);
        acc[3] = fmaf(v.w, v.w, acc[3]);
    }
    float* dst = partial2 + ((size_t)((t * 18 + lb) * 32) + chunk * 2 + half) * HW + p4 * 4;
    *(f32x4*)dst = acc;
}

// ---------------------------------------------------------------------------
// Kernel 2 (v2): finalize inverse norms (sum 32 subs).
// ---------------------------------------------------------------------------
__global__ __launch_bounds__(256) void norm_finalize2(const float* __restrict__ partial2,
                                                      float* __restrict__ invn) {
    int idx = blockIdx.x * 256 + threadIdx.x;
    if (idx >= 2 * 18 * HW) return;
    int t_lb = idx / HW;
    int ij = idx - t_lb * HW;
    const float* p = partial2 + (size_t)t_lb * 32 * HW + ij;
    float ss = 0.f;
    #pragma unroll
    for (int c = 0; c < 32; ++c) ss += p[c * HW];
    invn[idx] = 1.0f / fmaxf(sqrtf(ss), EPSF);
}

// ---------------------------------------------------------------------------
// Kernel 3a: transpose+convert: fq[lb][c][ij] -> At[li][ij][c] fp16 (ditto fs->Bt)
// ---------------------------------------------------------------------------
__global__ __launch_bounds__(256) void transpose_f16(const float* __restrict__ fq,
                                                     const float* __restrict__ fs,
                                                     ushort_t* __restrict__ At,
                                                     ushort_t* __restrict__ Bt,
                                                     int lb_base) {
    __shared__ float tile[64][65];
    int z = blockIdx.z;
    int tsel = z / 9, li = z - tsel * 9;
    int lb = lb_base + li;
    const float* src = (tsel ? fs : fq) + (size_t)lb * CF * HW;
    ushort_t* dst = (tsel ? Bt : At) + (size_t)li * HW * CF;
    int c0 = blockIdx.x * 64, ij0 = blockIdx.y * 64;
    int tid = threadIdx.x;
    int cl = tid >> 6;
    int col = tid & 63;
    #pragma unroll
    for (int rr = 0; rr < 16; ++rr) {
        int c_local = rr * 4 + cl;
        int ij = ij0 + col;
        tile[c_local][col] = (ij < HW) ? src[(size_t)(c0 + c_local) * HW + ij] : 0.f;
    }
    __syncthreads();
    int cp = (tid & 31) * 2;
    int rowsel = tid >> 5;
    #pragma unroll
    for (int rr = 0; rr < 8; ++rr) {
        int ij_local = rr * 8 + rowsel;
        int ij = ij0 + ij_local;
        if (ij < HW) {
            union { _Float16 h; ushort_t u; } h0, h1;
            h0.h = (_Float16)tile[cp][ij_local];
            h1.h = (_Float16)tile[cp + 1][ij_local];
            ushort2 o; o.x = h0.u; o.y = h1.u;
            *(ushort2*)(dst + (size_t)ij * CF + c0 + cp) = o;
        }
    }
}

// ---------------------------------------------------------------------------
// Kernel 3b: MFMA fp16 correlation GEMM -> f16 corr output (feeds convs only).
// ---------------------------------------------------------------------------
__global__ __launch_bounds__(256) void corr_gemm_mfma(const ushort_t* __restrict__ At,
                                                      const ushort_t* __restrict__ Bt,
                                                      const float* __restrict__ invn,
                                                      ushort_t* __restrict__ corr,
                                                      int lb_base) {
    __shared__ ushort_t As[64][72];
    __shared__ ushort_t Bs[64][72];
    int li = blockIdx.z, lb = lb_base + li;
    int l = lb >> 1, b = lb & 1;
    int i0 = blockIdx.y * 64, j0 = blockIdx.x * 64;
    int tid = threadIdx.x, lane = tid & 63, w = tid >> 6;
    int mw = (w >> 1) * 32, nw = (w & 1) * 32;
    f32x4 acc[2][2] = {};
    const ushort_t* Abase = At + (size_t)li * HW * CF;
    const ushort_t* Bbase = Bt + (size_t)li * HW * CF;

    for (int kt = 0; kt < 16; ++kt) {
        int c0 = kt * 64;
        __syncthreads();
        #pragma unroll
        for (int p = 0; p < 2; ++p) {
            int idx = tid + p * 256;
            int row = idx >> 3, c8 = idx & 7;
            uint4 va = make_uint4(0, 0, 0, 0), vb = make_uint4(0, 0, 0, 0);
            if (i0 + row < HW) va = *(const uint4*)(Abase + (size_t)(i0 + row) * CF + c0 + c8 * 8);
            if (j0 + row < HW) vb = *(const uint4*)(Bbase + (size_t)(j0 + row) * CF + c0 + c8 * 8);
            *(uint4*)&As[row][c8 * 8] = va;
            *(uint4*)&Bs[row][c8 * 8] = vb;
        }
        __syncthreads();
        #pragma unroll
        for (int ks = 0; ks < 2; ++ks) {
            int k0 = ks * 32 + (lane >> 4) * 8;
            half8 a0 = *(const half8*)&As[mw + (lane & 15)][k0];
            half8 a1 = *(const half8*)&As[mw + 16 + (lane & 15)][k0];
            half8 b0 = *(const half8*)&Bs[nw + (lane & 15)][k0];
            half8 b1 = *(const half8*)&Bs[nw + 16 + (lane & 15)][k0];
            acc[0][0] = __builtin_amdgcn_mfma_f32_16x16x32_f16(a0, b0, acc[0][0], 0, 0, 0);
            acc[0][1] = __builtin_amdgcn_mfma_f32_16x16x32_f16(a0, b1, acc[0][1], 0, 0, 0);
            acc[1][0] = __builtin_amdgcn_mfma_f32_16x16x32_f16(a1, b0, acc[1][0], 0, 0, 0);
            acc[1][1] = __builtin_amdgcn_mfma_f32_16x16x32_f16(a1, b1, acc[1][1], 0, 0, 0);
        }
    }
    int obase = (b * 9 + l) * HW;
    #pragma unroll
    for (int mi = 0; mi < 2; ++mi) {
        #pragma unroll
        for (int ni = 0; ni < 2; ++ni) {
            #pragma unroll
            for (int r = 0; r < 4; ++r) {
                int ij = i0 + mw + mi * 16 + (lane >> 4) * 4 + r;
                int km = j0 + nw + ni * 16 + (lane & 15);
                if (ij < HW && km < HW) {
                    union { _Float16 h; ushort_t u; } cv;
                    cv.h = (_Float16)(acc[mi][ni][r] * invn[lb * HW + ij] * invn[7200 + lb * HW + km]);
                    corr[(size_t)(obase + ij) * HW + km] = cv.u;
                }
            }
        }
    }
}

// ---------------------------------------------------------------------------
// Kernel W (v7): weight prep — dense-K B-fragment tables, fp16.
// wb[ch][dd][n16][k32]; global slot = ch*32+k over (ci,pl) space, zero-pad.
// ---------------------------------------------------------------------------
template <int CIN, int COUT, bool SWAP>
__global__ __launch_bounds__(256) void wprep7(const float* __restrict__ wt,
                                              ushort_t* __restrict__ wb) {
    constexpr int S = CIN * 9;
    constexpr int NCH = (S + 31) / 32;
    int idx = blockIdx.x * 256 + threadIdx.x;
    int total = NCH * 4608;
    if (idx >= total) return;
    int k = idx & 31, n = (idx >> 5) & 15, dd = (idx >> 9) % 9, ch = idx / 4608;
    int slot = ch * 32 + k;
    float v = 0.f;
    if (n < COUT && slot < S) {
        int ci = slot / 9, pl = slot - ci * 9;
        int di = pl / 3, dj = pl % 3, dk = dd / 3, dm = dd % 3;
        int widx = SWAP ? ((((n * CIN + ci) * 3 + dk) * 3 + dm) * 3 + di) * 3 + dj
                        : ((((n * CIN + ci) * 3 + di) * 3 + dj) * 3 + dk) * 3 + dm;
        v = wt[widx];
    }
    union { _Float16 h; ushort_t u; } cv; cv.h = (_Float16)v;
    wb[idx] = cv.u;
}

// ---------------------------------------------------------------------------
// Kernel 4 (v7): 4D conv + ReLU, MFMA implicit GEMM, f16.
// Dense 32-slot K-chunks over (ci,pl); compile-time unrolled chunk indices;
// b32 staging loads (2 km each, tid<200); register prefetch of next chunk
// issued before the MFMA phase (latency hidden); DUAL = two weight tables /
// two outputs sharing one staging (merged path A+B for layer 1).
// LDS Ah[484 rows][40 halfs] = 38.7 KB (4 blocks/CU), stride 80 B -> <=2-way.
// ---------------------------------------------------------------------------
template <int CIN, int COUT, bool DUAL, bool OUTF16, bool ACCUM>
__global__ __launch_bounds__(256) void conv4d_v7(const ushort_t* __restrict__ in,
                                                 const ushort_t* __restrict__ wbA,
                                                 const ushort_t* __restrict__ wbB,
                                                 void* __restrict__ outA,
                                                 void* __restrict__ outB) {
    constexpr int S = CIN * 9;
    constexpr int NCH = (S + 31) / 32;
    __shared__ __align__(16) ushort_t Ah[484 * 40];
    const int b = blockIdx.y, ij = blockIdx.x;
    const int i = ij / 20, j = ij - (ij / 20) * 20;
    const int tid = threadIdx.x, wv = tid >> 6, lane = tid & 63;
    const int m16 = lane & 15, q4 = lane >> 4;

    for (int p = tid; p < 484 * 20; p += 256) ((uint*)Ah)[p] = 0;

    // fragment-read row bases
    int baseh[7];
    #pragma unroll
    for (int s = 0; s < 7; ++s) {
        int t = wv + 4 * s;
        if (t < 25) {
            int km = t * 16 + m16;
            int kk = km / 20, mm = km - kk * 20;
            baseh[s] = (kk * 22 + mm) * 40 + q4 * 8;
        } else baseh[s] = 0;
    }
    f32x4 accA[7] = {};
    f32x4 accB[7] = {};

    // staging setup: thread owns km pair (2t, 2t+1); same LDS row pair r1, r1+1
    const bool stager = tid < 200;
    const int km1 = 2 * tid;
    const int r1 = stager ? ((km1 / 20 + 1) * 22 + (km1 % 20) + 1) : 0;
    int hofs[9]; bool vld[9];
    #pragma unroll
    for (int pl = 0; pl < 9; ++pl) {
        int ii = i + pl / 3 - 1, jj = j + pl % 3 - 1;
        vld[pl] = (unsigned)ii < 20u && (unsigned)jj < 20u;
        hofs[pl] = (ii * 20 + jj) * HW + km1;
    }
    const ushort_t* in_b = in + (size_t)b * CIN * HW * HW;
    const int wbase = m16 * 32 + q4 * 8;

    uint pf[32];
    // prefetch chunk 0
    #pragma unroll
    for (int u = 0; u < 32; ++u) {
        constexpr int dummy = 0; (void)dummy;
        int slot = u;
        if (slot < S) {
            int ci = slot / 9, pl = slot - ci * 9;
            pf[u] = (stager && vld[pl]) ? *(const uint*)(in_b + ci * (HW * HW) + hofs[pl]) : 0u;
        } else pf[u] = 0u;
    }
    __syncthreads();   // zeroing complete

    #pragma unroll
    for (int ch = 0; ch < NCH; ++ch) {
        // write pf -> LDS
        if (stager) {
            #pragma unroll
            for (int g4 = 0; g4 < 8; ++g4) {
                uint lo0 = (pf[4 * g4] & 0xFFFFu) | (pf[4 * g4 + 1] << 16);
                uint lo1 = (pf[4 * g4 + 2] & 0xFFFFu) | (pf[4 * g4 + 3] << 16);
                uint hi0 = (pf[4 * g4] >> 16) | (pf[4 * g4 + 1] & 0xFFFF0000u);
                uint hi1 = (pf[4 * g4 + 2] >> 16) | (pf[4 * g4 + 3] & 0xFFFF0000u);
                uint2 wlo; wlo.x = lo0; wlo.y = lo1;
                uint2 whi; whi.x = hi0; whi.y = hi1;
                *(uint2*)&Ah[(size_t)r1 * 40 + 4 * g4] = wlo;
                *(uint2*)&Ah[(size_t)(r1 + 1) * 40 + 4 * g4] = whi;
            }
        }
        __syncthreads();
        // prefetch next chunk (in flight during MFMA phase)
        if (ch + 1 < NCH) {
            #pragma unroll
            for (int u = 0; u < 32; ++u) {
                int slot = (ch + 1) * 32 + u;
                if (slot < S) {
                    int ci = slot / 9, pl = slot - ci * 9;
                    pf[u] = (stager && vld[pl]) ? *(const uint*)(in_b + ci * (HW * HW) + hofs[pl]) : 0u;
                } else pf[u] = 0u;
            }
        }
        // MFMA phase
        #pragma unroll
        for (int dd = 0; dd < 9; ++dd) {
            half8 bfA = *(const half8*)(wbA + (ch * 9 + dd) * 512 + wbase);
            half8 bfB;
            if (DUAL) bfB = *(const half8*)(wbB + (ch * 9 + dd) * 512 + wbase);
            const int doff = ((dd / 3) * 22 + (dd % 3)) * 40;
            #pragma unroll
            for (int s = 0; s < 7; ++s) {
                if (wv + 4 * s < 25) {
                    half8 af = *(const half8*)(Ah + baseh[s] + doff);
                    accA[s] = __builtin_amdgcn_mfma_f32_16x16x32_f16(af, bfA, accA[s], 0, 0, 0);
                    if (DUAL) accB[s] = __builtin_amdgcn_mfma_f32_16x16x32_f16(af, bfB, accB[s], 0, 0, 0);
                }
            }
        }
        if (ch + 1 < NCH) __syncthreads();   // readers done before next write
    }

    // epilogue: col=lane&15 -> co, row=q4*4+r -> km
    const int co = m16;
    if (co < COUT) {
        #pragma unroll
        for (int s = 0; s < 7; ++s) {
            int t = wv + 4 * s;
            if (t < 25) {
                int km0 = t * 16 + q4 * 4;
                size_t o = ((size_t)(b * COUT + co) * HW + ij) * HW + km0;
                if (OUTF16) {
                    union { ushort_t us[4]; uint2 u2; } pk;
                    #pragma unroll
                    for (int r = 0; r < 4; ++r) {
                        union { _Float16 h; ushort_t u16; } cv;
                        cv.h = (_Float16)fmaxf(accA[s][r], 0.f);
                        pk.us[r] = cv.u16;
                    }
                    *(uint2*)((ushort_t*)outA + o) = pk.u2;
                    if (DUAL) {
                        #pragma unroll
                        for (int r = 0; r < 4; ++r) {
                            union { _Float16 h; ushort_t u16; } cv;
                            cv.h = (_Float16)fmaxf(accB[s][r], 0.f);
                            pk.us[r] = cv.u16;
                        }
                        *(uint2*)((ushort_t*)outB + o) = pk.u2;
                    }
                } else {
                    float* op = (float*)outA + o;
                    #pragma unroll
                    for (int r = 0; r < 4; ++r) {
                        float v = fmaxf(accA[s][r], 0.f);
                        if (ACCUM) op[r] += v; else op[r] = v;
                    }
                }
            }
        }
    }
}

// ---------------------------------------------------------------------------
// Kernel F: f_s -> f16 padded copy fsh[b][c][416] (s >= 400 zero).
// ---------------------------------------------------------------------------
__global__ __launch_bounds__(256) void fs_prep(const float* __restrict__ f_s,
                                               ushort_t* __restrict__ fsh) {
    int idx = blockIdx.x * 256 + threadIdx.x;
    if (idx >= NB * CH * 416) return;
    int s = idx % 416, bc = idx / 416;
    float v = (s < HW) ? f_s[(size_t)bc * HW + s] : 0.f;
    union { _Float16 h; ushort_t u; } cv; cv.h = (_Float16)v;
    fsh[idx] = cv.u;
}

// ---------------------------------------------------------------------------
// Kernel 5 (v2): softmax + attn.V via MFMA.
// Block = 64 q-rows (grid 7 x NB). Phase 1: per-wave softmax (shfl reduce),
// P[64][424] f16 in LDS (stride 424 -> 2-way-free frag reads). Phase 2:
// D[q][c] = P[q][s] fsh[c][s]: full 16x16x32 tiles, B-frags from L2.
// ---------------------------------------------------------------------------
__global__ __launch_bounds__(256) void softmax_av_mfma(const float* __restrict__ c4,
                                                       const ushort_t* __restrict__ fsh,
                                                       float* __restrict__ att) {
    __shared__ ushort_t P[64 * 424];
    __shared__ float invl[64];
    const int b = blockIdx.y, qb = blockIdx.x * 64;
    const int tid = threadIdx.x, wv = tid >> 6, lane = tid & 63;
    const int m16 = lane & 15, q4 = lane >> 4;

    #pragma unroll 1
    for (int r = 0; r < 16; ++r) {
        int ql = wv * 16 + r;
        int q = qb + ql; if (q > HW - 1) q = HW - 1;
        const float* row = c4 + ((size_t)b * HW + q) * HW;
        float v[7];
        float mx = -1e30f;
        #pragma unroll
        for (int k = 0; k < 7; ++k) {
            int s = lane + 64 * k;
            v[k] = (s < HW) ? row[s] * TEMPF : -1e30f;
            mx = fmaxf(mx, v[k]);
        }
        #pragma unroll
        for (int off = 32; off; off >>= 1) mx = fmaxf(mx, __shfl_xor(mx, off, 64));
        float sum = 0.f;
        #pragma unroll
        for (int k = 0; k < 7; ++k) {
            int s = lane + 64 * k;
            if (s < HW) {
                float e = __expf(v[k] - mx);
                sum += e;
                union { _Float16 h; ushort_t u; } cv; cv.h = (_Float16)e;
                P[ql * 424 + s] = cv.u;
            } else if (s < 424) {
                P[ql * 424 + s] = 0;
            }
        }
        #pragma unroll
        for (int off = 32; off; off >>= 1) sum += __shfl_xor(sum, off, 64);
        if (lane == 0) invl[ql] = 1.0f / sum;
    }
    __syncthreads();

    half8 afr[13];
    #pragma unroll
    for (int ks = 0; ks < 13; ++ks)
        afr[ks] = *(const half8*)&P[(wv * 16 + m16) * 424 + ks * 32 + q4 * 8];
    const ushort_t* fb = fsh + (size_t)b * CH * 416;
    #pragma unroll 1
    for (int nt = 0; nt < 16; ++nt) {
        const ushort_t* fc = fb + (size_t)(nt * 16 + m16) * 416 + q4 * 8;
        f32x4 acc = {};
        #pragma unroll
        for (int ks = 0; ks < 13; ++ks) {
            half8 bf = *(const half8*)(fc + ks * 32);
            acc = __builtin_amdgcn_mfma_f32_16x16x32_f16(afr[ks], bf, acc, 0, 0, 0);
        }
        int c = nt * 16 + m16;
        #pragma unroll
        for (int r = 0; r < 4; ++r) {
            int ql = wv * 16 + q4 * 4 + r;
            int q = qb + ql;
            if (q < HW)
                att[((size_t)b * CH + c) * HW + q] = acc[r] * invl[ql];
        }
    }
}

// ---------------------------------------------------------------------------
// Kernel 6: fq = l2norm(f_q, ch) + 0.5 * l2norm(att_fq, ch)
// ---------------------------------------------------------------------------
__global__ __launch_bounds__(256) void final_fq(const float* __restrict__ f_q,
                                                const float* __restrict__ att,
                                                float* __restrict__ out_fq) {
    __shared__ float red[256];
    int b = blockIdx.y, q = blockIdx.x;
    int tid = threadIdx.x;
    size_t idx = (size_t)(b * CH + tid) * HW + q;
    float f = f_q[idx];
    float a = att[idx];
    red[tid] = f * f;
    __syncthreads();
    for (int s = 128; s > 0; s >>= 1) {
        if (tid < s) red[tid] += red[tid + s];
        __syncthreads();
    }
    float invf = 1.0f / fmaxf(sqrtf(red[0]), EPSF);
    __syncthreads();
    red[tid] = a * a;
    __syncthreads();
    for (int s = 128; s > 0; s >>= 1) {
        if (tid < s) red[tid] += red[tid + s];
        __syncthreads();
    }
    float inva = 1.0f / fmaxf(sqrtf(red[0]), EPSF);
    out_fq[idx] = f * invf + 0.5f * a * inva;
}

// ---------------------------------------------------------------------------
extern "C" void kernel_launch(void* const* d_in, const int* in_sizes, int n_in,
                              void* d_out, int out_size, void* d_ws, size_t ws_size,
                              hipStream_t stream) {
    const float* fq_feats = (const float*)d_in[0];
    const float* fs_feats = (const float*)d_in[1];
    const float* f_q      = (const float*)d_in[2];
    const float* f_s      = (const float*)d_in[3];
    const float* w1       = (const float*)d_in[4];
    const float* w2       = (const float*)d_in[5];
    const float* w3       = (const float*)d_in[6];
    float* out = (float*)d_out;              // fq at 0, att_fq at 204800

    float* ws      = (float*)d_ws;
    float* wbuf    = ws;                     // 115,200 fl: weight tables
    float* invn    = wbuf + 115200;          // 14,400
    float* corr    = invn + 14400;           // 2,880,000 fl (f16 corr lower half; fsh upper)
    float* buf1    = corr + 2880000;         // 3,200,000 (partial2 / At / b1A+b1B f16)
    float* buf2    = buf1 + 3200000;         // 3,200,000 (Bt / b2A+b2B f16)
    float* c4      = buf2 + 3200000;         // 320,000
    float* att     = out + 204800;

    float* partial2 = buf1;                  // 460,800 floats, dead after finalize
    ushort_t* corr_h = (ushort_t*)corr;      // 2,880,000 halfs
    ushort_t* fsh    = (ushort_t*)(corr + 1440000);   // 212,992 halfs
    ushort_t* At = (ushort_t*)buf1;
    ushort_t* Bt = (ushort_t*)buf2;
    ushort_t* b1A = (ushort_t*)buf1;
    ushort_t* b1B = b1A + 3200000;
    ushort_t* b2A = (ushort_t*)buf2;
    ushort_t* b2B = b2A + 3200000;

    // dense weight tables: each NCH=3 -> 13,824 halfs
    ushort_t* wb0   = (ushort_t*)wbuf;
    ushort_t* wbL1A = wb0;
    ushort_t* wbL1B = wb0 + 13824;
    ushort_t* wbL2A = wb0 + 27648;
    ushort_t* wbL2B = wb0 + 41472;
    ushort_t* wbL3A = wb0 + 55296;
    ushort_t* wbL3B = wb0 + 69120;           // ends 82,944 < 230,400 halfs ok

    norm_partial2<<<dim3(16, 18, 2), 256, 0, stream>>>(fq_feats, fs_feats, partial2);
    norm_finalize2<<<(2 * 18 * HW + 255) / 256, 256, 0, stream>>>(partial2, invn);

    wprep7<9, 10, false><<<54, 256, 0, stream>>>(w1, wbL1A);
    wprep7<9, 10, true ><<<54, 256, 0, stream>>>(w1, wbL1B);
    wprep7<10, 10, false><<<54, 256, 0, stream>>>(w2, wbL2A);
    wprep7<10, 10, true ><<<54, 256, 0, stream>>>(w2, wbL2B);
    wprep7<10, 1, false><<<54, 256, 0, stream>>>(w3, wbL3A);
    wprep7<10, 1, true ><<<54, 256, 0, stream>>>(w3, wbL3B);
    fs_prep<<<(NB * CH * 416 + 255) / 256, 256, 0, stream>>>(f_s, fsh);

    // correlation GEMM in two l-batches of 9 (buffers reused)
    for (int half = 0; half < 2; ++half) {
        int base = half * 9;
        transpose_f16<<<dim3(16, 7, 18), 256, 0, stream>>>(fq_feats, fs_feats, At, Bt, base);
        corr_gemm_mfma<<<dim3(7, 7, 9), 256, 0, stream>>>(At, Bt, invn, corr_h, base);
    }

    // L1: both paths from one staging (DUAL)
    conv4d_v7<9, 10, true, true, false><<<dim3(400, NB), 256, 0, stream>>>(corr_h, wbL1A, wbL1B, b1A, b1B);
    // L2 per path
    conv4d_v7<10, 10, false, true, false><<<dim3(400, NB), 256, 0, stream>>>(b1A, wbL2A, wbL2A, b2A, b2A);
    conv4d_v7<10, 10, false, true, false><<<dim3(400, NB), 256, 0, stream>>>(b1B, wbL2B, wbL2B, b2B, b2B);
    // L3 per path -> f32 c4 (second accumulates)
    conv4d_v7<10, 1, false, false, false><<<dim3(400, NB), 256, 0, stream>>>(b2A, wbL3A, wbL3A, c4, c4);
    conv4d_v7<10, 1, false, false, true ><<<dim3(400, NB), 256, 0, stream>>>(b2B, wbL3B, wbL3B, c4, c4);

    softmax_av_mfma<<<dim3(7, NB), 256, 0, stream>>>(c4, fsh, att);
    final_fq<<<dim3(400, NB), 256, 0, stream>>>(f_q, att, out);

    (void)in_sizes; (void)n_in; (void)out_size; (void)ws_size;
}

// Round 10
// 395.700 us; speedup vs baseline: 1.1145x; 1.1145x over previous
//
#include <hip/hip_runtime.h>
#include <math.h>
#include <stddef.h>

#define L9   9
#define NB   2
#define CF   1024
#define HW   400     // 20*20
#define CH   256
#define TEMPF 20.0f
#define EPSF  1e-12f

typedef _Float16 half8 __attribute__((ext_vector_type(8)));
typedef float f32x4 __attribute__((ext_vector_type(4)));
typedef unsigned short ushort_t;

// ---------------------------------------------------------------------------
// Kernel 1 (v2): sums of squares over C, vectorized float4 along ij.
// ---------------------------------------------------------------------------
__global__ __launch_bounds__(256) void norm_partial2(const float* __restrict__ fq,
                                                     const float* __restrict__ fs,
                                                     float* __restrict__ partial2) {
    int chunk = blockIdx.x, lb = blockIdx.y, t = blockIdx.z;
    int tid = threadIdx.x;
    if (tid >= 200) return;
    int half = tid / 100, p4 = tid - half * 100;
    const float* src = (t == 0 ? fq : fs) + (size_t)lb * CF * HW + p4 * 4;
    int c0 = chunk * 64 + half;
    f32x4 acc = {};
    #pragma unroll 8
    for (int it = 0; it < 32; ++it) {
        const float4 v = *(const float4*)(src + (size_t)(c0 + it * 2) * HW);
        acc[0] = fmaf(v.x, v.x, acc[0]);
        acc[1] = fmaf(v.y, v.y, acc[1]);
        acc[2] = fmaf(v.z, v.z, acc[2]);
        acc[3] = fmaf(v.w, v.w, acc[3]);
    }
    float* dst = partial2 + ((size_t)((t * 18 + lb) * 32) + chunk * 2 + half) * HW + p4 * 4;
    *(f32x4*)dst = acc;
}

// ---------------------------------------------------------------------------
// Kernel 2 (v2): finalize inverse norms (sum 32 subs).
// ---------------------------------------------------------------------------
__global__ __launch_bounds__(256) void norm_finalize2(const float* __restrict__ partial2,
                                                      float* __restrict__ invn) {
    int idx = blockIdx.x * 256 + threadIdx.x;
    if (idx >= 2 * 18 * HW) return;
    int t_lb = idx / HW;
    int ij = idx - t_lb * HW;
    const float* p = partial2 + (size_t)t_lb * 32 * HW + ij;
    float ss = 0.f;
    #pragma unroll
    for (int c = 0; c < 32; ++c) ss += p[c * HW];
    invn[idx] = 1.0f / fmaxf(sqrtf(ss), EPSF);
}

// ---------------------------------------------------------------------------
// Kernel 3a: transpose+convert: fq[lb][c][ij] -> At[li][ij][c] fp16 (ditto fs->Bt)
// ---------------------------------------------------------------------------
__global__ __launch_bounds__(256) void transpose_f16(const float* __restrict__ fq,
                                                     const float* __restrict__ fs,
                                                     ushort_t* __restrict__ At,
                                                     ushort_t* __restrict__ Bt,
                                                     int lb_base) {
    __shared__ float tile[64][65];
    int z = blockIdx.z;
    int tsel = z / 9, li = z - tsel * 9;
    int lb = lb_base + li;
    const float* src = (tsel ? fs : fq) + (size_t)lb * CF * HW;
    ushort_t* dst = (tsel ? Bt : At) + (size_t)li * HW * CF;
    int c0 = blockIdx.x * 64, ij0 = blockIdx.y * 64;
    int tid = threadIdx.x;
    int cl = tid >> 6;
    int col = tid & 63;
    #pragma unroll
    for (int rr = 0; rr < 16; ++rr) {
        int c_local = rr * 4 + cl;
        int ij = ij0 + col;
        tile[c_local][col] = (ij < HW) ? src[(size_t)(c0 + c_local) * HW + ij] : 0.f;
    }
    __syncthreads();
    int cp = (tid & 31) * 2;
    int rowsel = tid >> 5;
    #pragma unroll
    for (int rr = 0; rr < 8; ++rr) {
        int ij_local = rr * 8 + rowsel;
        int ij = ij0 + ij_local;
        if (ij < HW) {
            union { _Float16 h; ushort_t u; } h0, h1;
            h0.h = (_Float16)tile[cp][ij_local];
            h1.h = (_Float16)tile[cp + 1][ij_local];
            ushort2 o; o.x = h0.u; o.y = h1.u;
            *(ushort2*)(dst + (size_t)ij * CF + c0 + cp) = o;
        }
    }
}

// ---------------------------------------------------------------------------
// Kernel 3b: MFMA fp16 correlation GEMM -> f16 corr output (feeds convs only).
// ---------------------------------------------------------------------------
__global__ __launch_bounds__(256) void corr_gemm_mfma(const ushort_t* __restrict__ At,
                                                      const ushort_t* __restrict__ Bt,
                                                      const float* __restrict__ invn,
                                                      ushort_t* __restrict__ corr,
                                                      int lb_base) {
    __shared__ ushort_t As[64][72];
    __shared__ ushort_t Bs[64][72];
    int li = blockIdx.z, lb = lb_base + li;
    int l = lb >> 1, b = lb & 1;
    int i0 = blockIdx.y * 64, j0 = blockIdx.x * 64;
    int tid = threadIdx.x, lane = tid & 63, w = tid >> 6;
    int mw = (w >> 1) * 32, nw = (w & 1) * 32;
    f32x4 acc[2][2] = {};
    const ushort_t* Abase = At + (size_t)li * HW * CF;
    const ushort_t* Bbase = Bt + (size_t)li * HW * CF;

    for (int kt = 0; kt < 16; ++kt) {
        int c0 = kt * 64;
        __syncthreads();
        #pragma unroll
        for (int p = 0; p < 2; ++p) {
            int idx = tid + p * 256;
            int row = idx >> 3, c8 = idx & 7;
            uint4 va = make_uint4(0, 0, 0, 0), vb = make_uint4(0, 0, 0, 0);
            if (i0 + row < HW) va = *(const uint4*)(Abase + (size_t)(i0 + row) * CF + c0 + c8 * 8);
            if (j0 + row < HW) vb = *(const uint4*)(Bbase + (size_t)(j0 + row) * CF + c0 + c8 * 8);
            *(uint4*)&As[row][c8 * 8] = va;
            *(uint4*)&Bs[row][c8 * 8] = vb;
        }
        __syncthreads();
        #pragma unroll
        for (int ks = 0; ks < 2; ++ks) {
            int k0 = ks * 32 + (lane >> 4) * 8;
            half8 a0 = *(const half8*)&As[mw + (lane & 15)][k0];
            half8 a1 = *(const half8*)&As[mw + 16 + (lane & 15)][k0];
            half8 b0 = *(const half8*)&Bs[nw + (lane & 15)][k0];
            half8 b1 = *(const half8*)&Bs[nw + 16 + (lane & 15)][k0];
            acc[0][0] = __builtin_amdgcn_mfma_f32_16x16x32_f16(a0, b0, acc[0][0], 0, 0, 0);
            acc[0][1] = __builtin_amdgcn_mfma_f32_16x16x32_f16(a0, b1, acc[0][1], 0, 0, 0);
            acc[1][0] = __builtin_amdgcn_mfma_f32_16x16x32_f16(a1, b0, acc[1][0], 0, 0, 0);
            acc[1][1] = __builtin_amdgcn_mfma_f32_16x16x32_f16(a1, b1, acc[1][1], 0, 0, 0);
        }
    }
    int obase = (b * 9 + l) * HW;
    #pragma unroll
    for (int mi = 0; mi < 2; ++mi) {
        #pragma unroll
        for (int ni = 0; ni < 2; ++ni) {
            #pragma unroll
            for (int r = 0; r < 4; ++r) {
                int ij = i0 + mw + mi * 16 + (lane >> 4) * 4 + r;
                int km = j0 + nw + ni * 16 + (lane & 15);
                if (ij < HW && km < HW) {
                    union { _Float16 h; ushort_t u; } cv;
                    cv.h = (_Float16)(acc[mi][ni][r] * invn[lb * HW + ij] * invn[7200 + lb * HW + km]);
                    corr[(size_t)(obase + ij) * HW + km] = cv.u;
                }
            }
        }
    }
}

// ---------------------------------------------------------------------------
// Kernel W (v7): weight prep — dense-K B-fragment tables, fp16.
// ---------------------------------------------------------------------------
template <int CIN, int COUT, bool SWAP>
__global__ __launch_bounds__(256) void wprep7(const float* __restrict__ wt,
                                              ushort_t* __restrict__ wb) {
    constexpr int S = CIN * 9;
    constexpr int NCH = (S + 31) / 32;
    int idx = blockIdx.x * 256 + threadIdx.x;
    int total = NCH * 4608;
    if (idx >= total) return;
    int k = idx & 31, n = (idx >> 5) & 15, dd = (idx >> 9) % 9, ch = idx / 4608;
    int slot = ch * 32 + k;
    float v = 0.f;
    if (n < COUT && slot < S) {
        int ci = slot / 9, pl = slot - ci * 9;
        int di = pl / 3, dj = pl % 3, dk = dd / 3, dm = dd % 3;
        int widx = SWAP ? ((((n * CIN + ci) * 3 + dk) * 3 + dm) * 3 + di) * 3 + dj
                        : ((((n * CIN + ci) * 3 + di) * 3 + dj) * 3 + dk) * 3 + dm;
        v = wt[widx];
    }
    union { _Float16 h; ushort_t u; } cv; cv.h = (_Float16)v;
    wb[idx] = cv.u;
}

// ---------------------------------------------------------------------------
// Kernel 4 (v7): 4D conv + ReLU, MFMA implicit GEMM, f16 (verified R8).
// ---------------------------------------------------------------------------
template <int CIN, int COUT, bool DUAL, bool OUTF16, bool ACCUM>
__global__ __launch_bounds__(256) void conv4d_v7(const ushort_t* __restrict__ in,
                                                 const ushort_t* __restrict__ wbA,
                                                 const ushort_t* __restrict__ wbB,
                                                 void* __restrict__ outA,
                                                 void* __restrict__ outB) {
    constexpr int S = CIN * 9;
    constexpr int NCH = (S + 31) / 32;
    __shared__ __align__(16) ushort_t Ah[484 * 40];
    const int b = blockIdx.y, ij = blockIdx.x;
    const int i = ij / 20, j = ij - (ij / 20) * 20;
    const int tid = threadIdx.x, wv = tid >> 6, lane = tid & 63;
    const int m16 = lane & 15, q4 = lane >> 4;

    for (int p = tid; p < 484 * 20; p += 256) ((uint*)Ah)[p] = 0;

    int baseh[7];
    #pragma unroll
    for (int s = 0; s < 7; ++s) {
        int t = wv + 4 * s;
        if (t < 25) {
            int km = t * 16 + m16;
            int kk = km / 20, mm = km - kk * 20;
            baseh[s] = (kk * 22 + mm) * 40 + q4 * 8;
        } else baseh[s] = 0;
    }
    f32x4 accA[7] = {};
    f32x4 accB[7] = {};

    const bool stager = tid < 200;
    const int km1 = 2 * tid;
    const int r1 = stager ? ((km1 / 20 + 1) * 22 + (km1 % 20) + 1) : 0;
    int hofs[9]; bool vld[9];
    #pragma unroll
    for (int pl = 0; pl < 9; ++pl) {
        int ii = i + pl / 3 - 1, jj = j + pl % 3 - 1;
        vld[pl] = (unsigned)ii < 20u && (unsigned)jj < 20u;
        hofs[pl] = (ii * 20 + jj) * HW + km1;
    }
    const ushort_t* in_b = in + (size_t)b * CIN * HW * HW;
    const int wbase = m16 * 32 + q4 * 8;

    uint pf[32];
    #pragma unroll
    for (int u = 0; u < 32; ++u) {
        int slot = u;
        if (slot < S) {
            int ci = slot / 9, pl = slot - ci * 9;
            pf[u] = (stager && vld[pl]) ? *(const uint*)(in_b + ci * (HW * HW) + hofs[pl]) : 0u;
        } else pf[u] = 0u;
    }
    __syncthreads();

    #pragma unroll
    for (int ch = 0; ch < NCH; ++ch) {
        if (stager) {
            #pragma unroll
            for (int g4 = 0; g4 < 8; ++g4) {
                uint lo0 = (pf[4 * g4] & 0xFFFFu) | (pf[4 * g4 + 1] << 16);
                uint lo1 = (pf[4 * g4 + 2] & 0xFFFFu) | (pf[4 * g4 + 3] << 16);
                uint hi0 = (pf[4 * g4] >> 16) | (pf[4 * g4 + 1] & 0xFFFF0000u);
                uint hi1 = (pf[4 * g4 + 2] >> 16) | (pf[4 * g4 + 3] & 0xFFFF0000u);
                uint2 wlo; wlo.x = lo0; wlo.y = lo1;
                uint2 whi; whi.x = hi0; whi.y = hi1;
                *(uint2*)&Ah[(size_t)r1 * 40 + 4 * g4] = wlo;
                *(uint2*)&Ah[(size_t)(r1 + 1) * 40 + 4 * g4] = whi;
            }
        }
        __syncthreads();
        if (ch + 1 < NCH) {
            #pragma unroll
            for (int u = 0; u < 32; ++u) {
                int slot = (ch + 1) * 32 + u;
                if (slot < S) {
                    int ci = slot / 9, pl = slot - ci * 9;
                    pf[u] = (stager && vld[pl]) ? *(const uint*)(in_b + ci * (HW * HW) + hofs[pl]) : 0u;
                } else pf[u] = 0u;
            }
        }
        #pragma unroll
        for (int dd = 0; dd < 9; ++dd) {
            half8 bfA = *(const half8*)(wbA + (ch * 9 + dd) * 512 + wbase);
            half8 bfB;
            if (DUAL) bfB = *(const half8*)(wbB + (ch * 9 + dd) * 512 + wbase);
            const int doff = ((dd / 3) * 22 + (dd % 3)) * 40;
            #pragma unroll
            for (int s = 0; s < 7; ++s) {
                if (wv + 4 * s < 25) {
                    half8 af = *(const half8*)(Ah + baseh[s] + doff);
                    accA[s] = __builtin_amdgcn_mfma_f32_16x16x32_f16(af, bfA, accA[s], 0, 0, 0);
                    if (DUAL) accB[s] = __builtin_amdgcn_mfma_f32_16x16x32_f16(af, bfB, accB[s], 0, 0, 0);
                }
            }
        }
        if (ch + 1 < NCH) __syncthreads();
    }

    const int co = m16;
    if (co < COUT) {
        #pragma unroll
        for (int s = 0; s < 7; ++s) {
            int t = wv + 4 * s;
            if (t < 25) {
                int km0 = t * 16 + q4 * 4;
                size_t o = ((size_t)(b * COUT + co) * HW + ij) * HW + km0;
                if (OUTF16) {
                    union { ushort_t us[4]; uint2 u2; } pk;
                    #pragma unroll
                    for (int r = 0; r < 4; ++r) {
                        union { _Float16 h; ushort_t u16; } cv;
                        cv.h = (_Float16)fmaxf(accA[s][r], 0.f);
                        pk.us[r] = cv.u16;
                    }
                    *(uint2*)((ushort_t*)outA + o) = pk.u2;
                    if (DUAL) {
                        #pragma unroll
                        for (int r = 0; r < 4; ++r) {
                            union { _Float16 h; ushort_t u16; } cv;
                            cv.h = (_Float16)fmaxf(accB[s][r], 0.f);
                            pk.us[r] = cv.u16;
                        }
                        *(uint2*)((ushort_t*)outB + o) = pk.u2;
                    }
                } else {
                    float* op = (float*)outA + o;
                    #pragma unroll
                    for (int r = 0; r < 4; ++r) {
                        float v = fmaxf(accA[s][r], 0.f);
                        if (ACCUM) op[r] += v; else op[r] = v;
                    }
                }
            }
        }
    }
}

// ---------------------------------------------------------------------------
// Kernel F: f_s -> f16 padded copy fsh[b][c][416] (s >= 400 zero).
// ---------------------------------------------------------------------------
__global__ __launch_bounds__(256) void fs_prep(const float* __restrict__ f_s,
                                               ushort_t* __restrict__ fsh) {
    int idx = blockIdx.x * 256 + threadIdx.x;
    if (idx >= NB * CH * 416) return;
    int s = idx % 416, bc = idx / 416;
    float v = (s < HW) ? f_s[(size_t)bc * HW + s] : 0.f;
    union { _Float16 h; ushort_t u; } cv; cv.h = (_Float16)v;
    fsh[idx] = cv.u;
}

// ---------------------------------------------------------------------------
// Kernel 5 (v3): softmax + attn.V via MFMA, parallelized.
// Grid (7 qtiles, 8 nsplits, NB) = 112 blocks. Block = 4 waves; wave w owns
// q-rows qb+w*16..+15 and 2 nt tiles (blockIdx.y*2+{0,1}). Waves fully
// independent (no __syncthreads). Phase 1: 4 iterations x 4 rows (16-lane
// groups, float4 loads, width-16 shfl reduce) -> P f16 in LDS + invl.
// Phase 2: D[q][c] = P[q][s] fsh[c][s] via 16x16x32 MFMA.
// ---------------------------------------------------------------------------
__global__ __launch_bounds__(256) void softmax_av_mfma2(const float* __restrict__ c4,
                                                        const ushort_t* __restrict__ fsh,
                                                        float* __restrict__ att) {
    __shared__ ushort_t P[64 * 424];
    __shared__ float invl[64];
    const int b = blockIdx.z, qb = blockIdx.x * 64;
    const int tid = threadIdx.x, wv = tid >> 6, lane = tid & 63;
    const int m16 = lane & 15, q4 = lane >> 4;
    const int lane16 = lane & 15, rg4 = lane >> 4;

    // ---- phase 1: softmax of this wave's 16 rows, 4 rows at a time ----
    #pragma unroll 1
    for (int rg = 0; rg < 4; ++rg) {
        const int ql = wv * 16 + rg * 4 + rg4;
        int q = qb + ql; if (q > HW - 1) q = HW - 1;
        const float* row = c4 + ((size_t)b * HW + q) * HW;
        float4 v4[7];
        #pragma unroll
        for (int k4 = 0; k4 < 6; ++k4)
            v4[k4] = *(const float4*)(row + 64 * k4 + lane16 * 4);
        v4[6] = (lane16 < 4) ? *(const float4*)(row + 384 + lane16 * 4)
                             : make_float4(-1e30f, -1e30f, -1e30f, -1e30f);
        float mx = -1e30f;
        #pragma unroll
        for (int k4 = 0; k4 < 7; ++k4) {
            mx = fmaxf(mx, fmaxf(fmaxf(v4[k4].x, v4[k4].y), fmaxf(v4[k4].z, v4[k4].w)));
        }
        #pragma unroll
        for (int off = 8; off; off >>= 1) mx = fmaxf(mx, __shfl_xor(mx, off, 16));
        float sum = 0.f;
        #pragma unroll
        for (int k4 = 0; k4 < 7; ++k4) {
            if (k4 == 6 && lane16 >= 4) break;
            float e0 = __expf(fmaf(TEMPF, v4[k4].x / 1.0f, 0.f) * 0.f + (v4[k4].x * TEMPF - mx * TEMPF));
            // simple: e = exp(TEMP*(v - mx))
            e0 = __expf(TEMPF * (v4[k4].x - mx));
            float e1 = __expf(TEMPF * (v4[k4].y - mx));
            float e2 = __expf(TEMPF * (v4[k4].z - mx));
            float e3 = __expf(TEMPF * (v4[k4].w - mx));
            sum += e0 + e1 + e2 + e3;
            union { ushort_t us[4]; uint2 u2; } pk;
            union { _Float16 h; ushort_t u16; } cv;
            cv.h = (_Float16)e0; pk.us[0] = cv.u16;
            cv.h = (_Float16)e1; pk.us[1] = cv.u16;
            cv.h = (_Float16)e2; pk.us[2] = cv.u16;
            cv.h = (_Float16)e3; pk.us[3] = cv.u16;
            *(uint2*)&P[(size_t)ql * 424 + 64 * k4 + lane16 * 4] = pk.u2;
        }
        // zero pad s in [400,424): k4==6 slots for lane16 4..9
        if (lane16 >= 4 && lane16 < 10) {
            uint2 z2; z2.x = 0; z2.y = 0;
            *(uint2*)&P[(size_t)ql * 424 + 384 + lane16 * 4] = z2;
        }
        #pragma unroll
        for (int off = 8; off; off >>= 1) sum += __shfl_xor(sum, off, 16);
        if (lane16 == 0) invl[ql] = 1.0f / sum;
    }

    // ---- phase 2: AV GEMM for this wave's 16 rows x 2 nt tiles ----
    half8 afr[13];
    #pragma unroll
    for (int ks = 0; ks < 13; ++ks)
        afr[ks] = *(const half8*)&P[(size_t)(wv * 16 + m16) * 424 + ks * 32 + q4 * 8];
    const ushort_t* fb = fsh + (size_t)b * CH * 416;
    #pragma unroll
    for (int ntl = 0; ntl < 2; ++ntl) {
        const int nt = blockIdx.y * 2 + ntl;
        const int c = nt * 16 + m16;
        const ushort_t* fc = fb + (size_t)c * 416 + q4 * 8;
        f32x4 acc = {};
        #pragma unroll
        for (int ks = 0; ks < 13; ++ks) {
            half8 bf = *(const half8*)(fc + ks * 32);
            acc = __builtin_amdgcn_mfma_f32_16x16x32_f16(afr[ks], bf, acc, 0, 0, 0);
        }
        #pragma unroll
        for (int r = 0; r < 4; ++r) {
            int ql = wv * 16 + q4 * 4 + r;
            int q = qb + ql;
            if (q < HW)
                att[((size_t)b * CH + c) * HW + q] = acc[r] * invl[ql];
        }
    }
}

// ---------------------------------------------------------------------------
// Kernel 6: fq = l2norm(f_q, ch) + 0.5 * l2norm(att_fq, ch)
// ---------------------------------------------------------------------------
__global__ __launch_bounds__(256) void final_fq(const float* __restrict__ f_q,
                                                const float* __restrict__ att,
                                                float* __restrict__ out_fq) {
    __shared__ float red[256];
    int b = blockIdx.y, q = blockIdx.x;
    int tid = threadIdx.x;
    size_t idx = (size_t)(b * CH + tid) * HW + q;
    float f = f_q[idx];
    float a = att[idx];
    red[tid] = f * f;
    __syncthreads();
    for (int s = 128; s > 0; s >>= 1) {
        if (tid < s) red[tid] += red[tid + s];
        __syncthreads();
    }
    float invf = 1.0f / fmaxf(sqrtf(red[0]), EPSF);
    __syncthreads();
    red[tid] = a * a;
    __syncthreads();
    for (int s = 128; s > 0; s >>= 1) {
        if (tid < s) red[tid] += red[tid + s];
        __syncthreads();
    }
    float inva = 1.0f / fmaxf(sqrtf(red[0]), EPSF);
    out_fq[idx] = f * invf + 0.5f * a * inva;
}

// ---------------------------------------------------------------------------
extern "C" void kernel_launch(void* const* d_in, const int* in_sizes, int n_in,
                              void* d_out, int out_size, void* d_ws, size_t ws_size,
                              hipStream_t stream) {
    const float* fq_feats = (const float*)d_in[0];
    const float* fs_feats = (const float*)d_in[1];
    const float* f_q      = (const float*)d_in[2];
    const float* f_s      = (const float*)d_in[3];
    const float* w1       = (const float*)d_in[4];
    const float* w2       = (const float*)d_in[5];
    const float* w3       = (const float*)d_in[6];
    float* out = (float*)d_out;              // fq at 0, att_fq at 204800

    float* ws      = (float*)d_ws;
    float* wbuf    = ws;                     // 115,200 fl: weight tables
    float* invn    = wbuf + 115200;          // 14,400
    float* corr    = invn + 14400;           // 2,880,000 fl (f16 corr lower half; fsh upper)
    float* buf1    = corr + 2880000;         // 3,200,000 (partial2 / At / b1A+b1B f16)
    float* buf2    = buf1 + 3200000;         // 3,200,000 (Bt / b2A+b2B f16)
    float* c4      = buf2 + 3200000;         // 320,000
    float* att     = out + 204800;

    float* partial2 = buf1;
    ushort_t* corr_h = (ushort_t*)corr;
    ushort_t* fsh    = (ushort_t*)(corr + 1440000);
    ushort_t* At = (ushort_t*)buf1;
    ushort_t* Bt = (ushort_t*)buf2;
    ushort_t* b1A = (ushort_t*)buf1;
    ushort_t* b1B = b1A + 3200000;
    ushort_t* b2A = (ushort_t*)buf2;
    ushort_t* b2B = b2A + 3200000;

    ushort_t* wb0   = (ushort_t*)wbuf;
    ushort_t* wbL1A = wb0;
    ushort_t* wbL1B = wb0 + 13824;
    ushort_t* wbL2A = wb0 + 27648;
    ushort_t* wbL2B = wb0 + 41472;
    ushort_t* wbL3A = wb0 + 55296;
    ushort_t* wbL3B = wb0 + 69120;

    norm_partial2<<<dim3(16, 18, 2), 256, 0, stream>>>(fq_feats, fs_feats, partial2);
    norm_finalize2<<<(2 * 18 * HW + 255) / 256, 256, 0, stream>>>(partial2, invn);

    wprep7<9, 10, false><<<54, 256, 0, stream>>>(w1, wbL1A);
    wprep7<9, 10, true ><<<54, 256, 0, stream>>>(w1, wbL1B);
    wprep7<10, 10, false><<<54, 256, 0, stream>>>(w2, wbL2A);
    wprep7<10, 10, true ><<<54, 256, 0, stream>>>(w2, wbL2B);
    wprep7<10, 1, false><<<54, 256, 0, stream>>>(w3, wbL3A);
    wprep7<10, 1, true ><<<54, 256, 0, stream>>>(w3, wbL3B);
    fs_prep<<<(NB * CH * 416 + 255) / 256, 256, 0, stream>>>(f_s, fsh);

    for (int half = 0; half < 2; ++half) {
        int base = half * 9;
        transpose_f16<<<dim3(16, 7, 18), 256, 0, stream>>>(fq_feats, fs_feats, At, Bt, base);
        corr_gemm_mfma<<<dim3(7, 7, 9), 256, 0, stream>>>(At, Bt, invn, corr_h, base);
    }

    conv4d_v7<9, 10, true, true, false><<<dim3(400, NB), 256, 0, stream>>>(corr_h, wbL1A, wbL1B, b1A, b1B);
    conv4d_v7<10, 10, false, true, false><<<dim3(400, NB), 256, 0, stream>>>(b1A, wbL2A, wbL2A, b2A, b2A);
    conv4d_v7<10, 10, false, true, false><<<dim3(400, NB), 256, 0, stream>>>(b1B, wbL2B, wbL2B, b2B, b2B);
    conv4d_v7<10, 1, false, false, false><<<dim3(400, NB), 256, 0, stream>>>(b2A, wbL3A, wbL3A, c4, c4);
    conv4d_v7<10, 1, false, false, true ><<<dim3(400, NB), 256, 0, stream>>>(b2B, wbL3B, wbL3B, c4, c4);

    softmax_av_mfma2<<<dim3(7, 8, NB), 256, 0, stream>>>(c4, fsh, att);
    final_fq<<<dim3(400, NB), 256, 0, stream>>>(f_q, att, out);

    (void)in_sizes; (void)n_in; (void)out_size; (void)ws_size;
}

// Round 11
// 359.240 us; speedup vs baseline: 1.2276x; 1.1015x over previous
//
#include <hip/hip_runtime.h>
#include <math.h>
#include <stddef.h>

#define L9   9
#define NB   2
#define CF   1024
#define HW   400     // 20*20
#define CH   256
#define TEMPF 20.0f
#define EPSF  1e-12f

typedef _Float16 half8 __attribute__((ext_vector_type(8)));
typedef float f32x4 __attribute__((ext_vector_type(4)));
typedef unsigned short ushort_t;

// ---------------------------------------------------------------------------
// Kernel 1 (v2): sums of squares over C, vectorized float4 along ij.
// ---------------------------------------------------------------------------
__global__ __launch_bounds__(256) void norm_partial2(const float* __restrict__ fq,
                                                     const float* __restrict__ fs,
                                                     float* __restrict__ partial2) {
    int chunk = blockIdx.x, lb = blockIdx.y, t = blockIdx.z;
    int tid = threadIdx.x;
    if (tid >= 200) return;
    int half = tid / 100, p4 = tid - half * 100;
    const float* src = (t == 0 ? fq : fs) + (size_t)lb * CF * HW + p4 * 4;
    int c0 = chunk * 64 + half;
    f32x4 acc = {};
    #pragma unroll 8
    for (int it = 0; it < 32; ++it) {
        const float4 v = *(const float4*)(src + (size_t)(c0 + it * 2) * HW);
        acc[0] = fmaf(v.x, v.x, acc[0]);
        acc[1] = fmaf(v.y, v.y, acc[1]);
        acc[2] = fmaf(v.z, v.z, acc[2]);
        acc[3] = fmaf(v.w, v.w, acc[3]);
    }
    float* dst = partial2 + ((size_t)((t * 18 + lb) * 32) + chunk * 2 + half) * HW + p4 * 4;
    *(f32x4*)dst = acc;
}

// ---------------------------------------------------------------------------
// Kernel 2 (v2): finalize inverse norms (sum 32 subs).
// ---------------------------------------------------------------------------
__global__ __launch_bounds__(256) void norm_finalize2(const float* __restrict__ partial2,
                                                      float* __restrict__ invn) {
    int idx = blockIdx.x * 256 + threadIdx.x;
    if (idx >= 2 * 18 * HW) return;
    int t_lb = idx / HW;
    int ij = idx - t_lb * HW;
    const float* p = partial2 + (size_t)t_lb * 32 * HW + ij;
    float ss = 0.f;
    #pragma unroll
    for (int c = 0; c < 32; ++c) ss += p[c * HW];
    invn[idx] = 1.0f / fmaxf(sqrtf(ss), EPSF);
}

// ---------------------------------------------------------------------------
// Kernel 3a: transpose+convert: fq[lb][c][ij] -> At[li][ij][c] fp16 (ditto fs->Bt)
// ---------------------------------------------------------------------------
__global__ __launch_bounds__(256) void transpose_f16(const float* __restrict__ fq,
                                                     const float* __restrict__ fs,
                                                     ushort_t* __restrict__ At,
                                                     ushort_t* __restrict__ Bt,
                                                     int lb_base) {
    __shared__ float tile[64][65];
    int z = blockIdx.z;
    int tsel = z / 9, li = z - tsel * 9;
    int lb = lb_base + li;
    const float* src = (tsel ? fs : fq) + (size_t)lb * CF * HW;
    ushort_t* dst = (tsel ? Bt : At) + (size_t)li * HW * CF;
    int c0 = blockIdx.x * 64, ij0 = blockIdx.y * 64;
    int tid = threadIdx.x;
    int cl = tid >> 6;
    int col = tid & 63;
    #pragma unroll
    for (int rr = 0; rr < 16; ++rr) {
        int c_local = rr * 4 + cl;
        int ij = ij0 + col;
        tile[c_local][col] = (ij < HW) ? src[(size_t)(c0 + c_local) * HW + ij] : 0.f;
    }
    __syncthreads();
    int cp = (tid & 31) * 2;
    int rowsel = tid >> 5;
    #pragma unroll
    for (int rr = 0; rr < 8; ++rr) {
        int ij_local = rr * 8 + rowsel;
        int ij = ij0 + ij_local;
        if (ij < HW) {
            union { _Float16 h; ushort_t u; } h0, h1;
            h0.h = (_Float16)tile[cp][ij_local];
            h1.h = (_Float16)tile[cp + 1][ij_local];
            ushort2 o; o.x = h0.u; o.y = h1.u;
            *(ushort2*)(dst + (size_t)ij * CF + c0 + cp) = o;
        }
    }
}

// ---------------------------------------------------------------------------
// Kernel 3b: MFMA fp16 correlation GEMM -> f16 corr output (feeds convs only).
// ---------------------------------------------------------------------------
__global__ __launch_bounds__(256) void corr_gemm_mfma(const ushort_t* __restrict__ At,
                                                      const ushort_t* __restrict__ Bt,
                                                      const float* __restrict__ invn,
                                                      ushort_t* __restrict__ corr,
                                                      int lb_base) {
    __shared__ ushort_t As[64][72];
    __shared__ ushort_t Bs[64][72];
    int li = blockIdx.z, lb = lb_base + li;
    int l = lb >> 1, b = lb & 1;
    int i0 = blockIdx.y * 64, j0 = blockIdx.x * 64;
    int tid = threadIdx.x, lane = tid & 63, w = tid >> 6;
    int mw = (w >> 1) * 32, nw = (w & 1) * 32;
    f32x4 acc[2][2] = {};
    const ushort_t* Abase = At + (size_t)li * HW * CF;
    const ushort_t* Bbase = Bt + (size_t)li * HW * CF;

    for (int kt = 0; kt < 16; ++kt) {
        int c0 = kt * 64;
        __syncthreads();
        #pragma unroll
        for (int p = 0; p < 2; ++p) {
            int idx = tid + p * 256;
            int row = idx >> 3, c8 = idx & 7;
            uint4 va = make_uint4(0, 0, 0, 0), vb = make_uint4(0, 0, 0, 0);
            if (i0 + row < HW) va = *(const uint4*)(Abase + (size_t)(i0 + row) * CF + c0 + c8 * 8);
            if (j0 + row < HW) vb = *(const uint4*)(Bbase + (size_t)(j0 + row) * CF + c0 + c8 * 8);
            *(uint4*)&As[row][c8 * 8] = va;
            *(uint4*)&Bs[row][c8 * 8] = vb;
        }
        __syncthreads();
        #pragma unroll
        for (int ks = 0; ks < 2; ++ks) {
            int k0 = ks * 32 + (lane >> 4) * 8;
            half8 a0 = *(const half8*)&As[mw + (lane & 15)][k0];
            half8 a1 = *(const half8*)&As[mw + 16 + (lane & 15)][k0];
            half8 b0 = *(const half8*)&Bs[nw + (lane & 15)][k0];
            half8 b1 = *(const half8*)&Bs[nw + 16 + (lane & 15)][k0];
            acc[0][0] = __builtin_amdgcn_mfma_f32_16x16x32_f16(a0, b0, acc[0][0], 0, 0, 0);
            acc[0][1] = __builtin_amdgcn_mfma_f32_16x16x32_f16(a0, b1, acc[0][1], 0, 0, 0);
            acc[1][0] = __builtin_amdgcn_mfma_f32_16x16x32_f16(a1, b0, acc[1][0], 0, 0, 0);
            acc[1][1] = __builtin_amdgcn_mfma_f32_16x16x32_f16(a1, b1, acc[1][1], 0, 0, 0);
        }
    }
    int obase = (b * 9 + l) * HW;
    #pragma unroll
    for (int mi = 0; mi < 2; ++mi) {
        #pragma unroll
        for (int ni = 0; ni < 2; ++ni) {
            #pragma unroll
            for (int r = 0; r < 4; ++r) {
                int ij = i0 + mw + mi * 16 + (lane >> 4) * 4 + r;
                int km = j0 + nw + ni * 16 + (lane & 15);
                if (ij < HW && km < HW) {
                    union { _Float16 h; ushort_t u; } cv;
                    cv.h = (_Float16)(acc[mi][ni][r] * invn[lb * HW + ij] * invn[7200 + lb * HW + km]);
                    corr[(size_t)(obase + ij) * HW + km] = cv.u;
                }
            }
        }
    }
}

// ---------------------------------------------------------------------------
// Kernel W (v7): weight prep — dense-K B-fragment tables, fp16.
// ---------------------------------------------------------------------------
template <int CIN, int COUT, bool SWAP>
__global__ __launch_bounds__(256) void wprep7(const float* __restrict__ wt,
                                              ushort_t* __restrict__ wb) {
    constexpr int S = CIN * 9;
    constexpr int NCH = (S + 31) / 32;
    int idx = blockIdx.x * 256 + threadIdx.x;
    int total = NCH * 4608;
    if (idx >= total) return;
    int k = idx & 31, n = (idx >> 5) & 15, dd = (idx >> 9) % 9, ch = idx / 4608;
    int slot = ch * 32 + k;
    float v = 0.f;
    if (n < COUT && slot < S) {
        int ci = slot / 9, pl = slot - ci * 9;
        int di = pl / 3, dj = pl % 3, dk = dd / 3, dm = dd % 3;
        int widx = SWAP ? ((((n * CIN + ci) * 3 + dk) * 3 + dm) * 3 + di) * 3 + dj
                        : ((((n * CIN + ci) * 3 + di) * 3 + dj) * 3 + dk) * 3 + dm;
        v = wt[widx];
    }
    union { _Float16 h; ushort_t u; } cv; cv.h = (_Float16)v;
    wb[idx] = cv.u;
}

// ---------------------------------------------------------------------------
// Kernel 4 (v8): 4D conv + ReLU, MFMA implicit GEMM, f16.
// As v7 (verified R9) plus grid-z path merging: when !DUAL, blockIdx.z
// selects (in, wb, out) A/B — one dispatch covers both conv paths (1600
// blocks -> 6.25 blocks/CU available, LDS-capped 4 resident -> staging of
// one block hides behind MFMA of others). DUAL (L1) shares one staging for
// both weight tables. Outputs always direct-store (no ACCUM).
// ---------------------------------------------------------------------------
template <int CIN, int COUT, bool DUAL, bool OUTF16>
__global__ __launch_bounds__(256) void conv4d_v8(const ushort_t* __restrict__ inA,
                                                 const ushort_t* __restrict__ inB,
                                                 const ushort_t* __restrict__ wbA,
                                                 const ushort_t* __restrict__ wbB,
                                                 void* __restrict__ outA,
                                                 void* __restrict__ outB) {
    constexpr int S = CIN * 9;
    constexpr int NCH = (S + 31) / 32;
    __shared__ __align__(16) ushort_t Ah[484 * 40];
    const int b = blockIdx.y, ij = blockIdx.x;
    const int z = blockIdx.z;
    const ushort_t* in = (DUAL || z == 0) ? inA : inB;
    const ushort_t* wbS = (DUAL || z == 0) ? wbA : wbB;
    void* outS = (DUAL || z == 0) ? outA : outB;
    const int i = ij / 20, j = ij - (ij / 20) * 20;
    const int tid = threadIdx.x, wv = tid >> 6, lane = tid & 63;
    const int m16 = lane & 15, q4 = lane >> 4;

    for (int p = tid; p < 484 * 20; p += 256) ((uint*)Ah)[p] = 0;

    int baseh[7];
    #pragma unroll
    for (int s = 0; s < 7; ++s) {
        int t = wv + 4 * s;
        if (t < 25) {
            int km = t * 16 + m16;
            int kk = km / 20, mm = km - kk * 20;
            baseh[s] = (kk * 22 + mm) * 40 + q4 * 8;
        } else baseh[s] = 0;
    }
    f32x4 accA[7] = {};
    f32x4 accB[7] = {};

    const bool stager = tid < 200;
    const int km1 = 2 * tid;
    const int r1 = stager ? ((km1 / 20 + 1) * 22 + (km1 % 20) + 1) : 0;
    int hofs[9]; bool vld[9];
    #pragma unroll
    for (int pl = 0; pl < 9; ++pl) {
        int ii = i + pl / 3 - 1, jj = j + pl % 3 - 1;
        vld[pl] = (unsigned)ii < 20u && (unsigned)jj < 20u;
        hofs[pl] = (ii * 20 + jj) * HW + km1;
    }
    const ushort_t* in_b = in + (size_t)b * CIN * HW * HW;
    const int wbase = m16 * 32 + q4 * 8;

    uint pf[32];
    #pragma unroll
    for (int u = 0; u < 32; ++u) {
        int slot = u;
        if (slot < S) {
            int ci = slot / 9, pl = slot - ci * 9;
            pf[u] = (stager && vld[pl]) ? *(const uint*)(in_b + ci * (HW * HW) + hofs[pl]) : 0u;
        } else pf[u] = 0u;
    }
    __syncthreads();

    #pragma unroll
    for (int ch = 0; ch < NCH; ++ch) {
        if (stager) {
            #pragma unroll
            for (int g4 = 0; g4 < 8; ++g4) {
                uint lo0 = (pf[4 * g4] & 0xFFFFu) | (pf[4 * g4 + 1] << 16);
                uint lo1 = (pf[4 * g4 + 2] & 0xFFFFu) | (pf[4 * g4 + 3] << 16);
                uint hi0 = (pf[4 * g4] >> 16) | (pf[4 * g4 + 1] & 0xFFFF0000u);
                uint hi1 = (pf[4 * g4 + 2] >> 16) | (pf[4 * g4 + 3] & 0xFFFF0000u);
                uint2 wlo; wlo.x = lo0; wlo.y = lo1;
                uint2 whi; whi.x = hi0; whi.y = hi1;
                *(uint2*)&Ah[(size_t)r1 * 40 + 4 * g4] = wlo;
                *(uint2*)&Ah[(size_t)(r1 + 1) * 40 + 4 * g4] = whi;
            }
        }
        __syncthreads();
        if (ch + 1 < NCH) {
            #pragma unroll
            for (int u = 0; u < 32; ++u) {
                int slot = (ch + 1) * 32 + u;
                if (slot < S) {
                    int ci = slot / 9, pl = slot - ci * 9;
                    pf[u] = (stager && vld[pl]) ? *(const uint*)(in_b + ci * (HW * HW) + hofs[pl]) : 0u;
                } else pf[u] = 0u;
            }
        }
        #pragma unroll
        for (int dd = 0; dd < 9; ++dd) {
            half8 bfA = *(const half8*)(wbS + (ch * 9 + dd) * 512 + wbase);
            half8 bfB;
            if (DUAL) bfB = *(const half8*)(wbB + (ch * 9 + dd) * 512 + wbase);
            const int doff = ((dd / 3) * 22 + (dd % 3)) * 40;
            #pragma unroll
            for (int s = 0; s < 7; ++s) {
                if (wv + 4 * s < 25) {
                    half8 af = *(const half8*)(Ah + baseh[s] + doff);
                    accA[s] = __builtin_amdgcn_mfma_f32_16x16x32_f16(af, bfA, accA[s], 0, 0, 0);
                    if (DUAL) accB[s] = __builtin_amdgcn_mfma_f32_16x16x32_f16(af, bfB, accB[s], 0, 0, 0);
                }
            }
        }
        if (ch + 1 < NCH) __syncthreads();
    }

    const int co = m16;
    if (co < COUT) {
        #pragma unroll
        for (int s = 0; s < 7; ++s) {
            int t = wv + 4 * s;
            if (t < 25) {
                int km0 = t * 16 + q4 * 4;
                size_t o = ((size_t)(b * COUT + co) * HW + ij) * HW + km0;
                if (OUTF16) {
                    union { ushort_t us[4]; uint2 u2; } pk;
                    #pragma unroll
                    for (int r = 0; r < 4; ++r) {
                        union { _Float16 h; ushort_t u16; } cv;
                        cv.h = (_Float16)fmaxf(accA[s][r], 0.f);
                        pk.us[r] = cv.u16;
                    }
                    *(uint2*)((ushort_t*)outS + o) = pk.u2;
                    if (DUAL) {
                        #pragma unroll
                        for (int r = 0; r < 4; ++r) {
                            union { _Float16 h; ushort_t u16; } cv;
                            cv.h = (_Float16)fmaxf(accB[s][r], 0.f);
                            pk.us[r] = cv.u16;
                        }
                        *(uint2*)((ushort_t*)outB + o) = pk.u2;
                    }
                } else {
                    float* op = (float*)outS + o;
                    #pragma unroll
                    for (int r = 0; r < 4; ++r)
                        op[r] = fmaxf(accA[s][r], 0.f);
                }
            }
        }
    }
}

// ---------------------------------------------------------------------------
// Kernel F: f_s -> f16 padded copy fsh[b][c][416] (s >= 400 zero).
// ---------------------------------------------------------------------------
__global__ __launch_bounds__(256) void fs_prep(const float* __restrict__ f_s,
                                               ushort_t* __restrict__ fsh) {
    int idx = blockIdx.x * 256 + threadIdx.x;
    if (idx >= NB * CH * 416) return;
    int s = idx % 416, bc = idx / 416;
    float v = (s < HW) ? f_s[(size_t)bc * HW + s] : 0.f;
    union { _Float16 h; ushort_t u; } cv; cv.h = (_Float16)v;
    fsh[idx] = cv.u;
}

// ---------------------------------------------------------------------------
// Kernel 5 (v3): softmax + attn.V via MFMA (verified R9), now summing the
// two L3 path outputs (c4A + c4B) in phase 1.
// ---------------------------------------------------------------------------
__global__ __launch_bounds__(256) void softmax_av_mfma2(const float* __restrict__ c4A,
                                                        const float* __restrict__ c4B,
                                                        const ushort_t* __restrict__ fsh,
                                                        float* __restrict__ att) {
    __shared__ ushort_t P[64 * 424];
    __shared__ float invl[64];
    const int b = blockIdx.z, qb = blockIdx.x * 64;
    const int tid = threadIdx.x, wv = tid >> 6, lane = tid & 63;
    const int m16 = lane & 15, q4 = lane >> 4;
    const int lane16 = lane & 15, rg4 = lane >> 4;

    // ---- phase 1: softmax of this wave's 16 rows, 4 rows at a time ----
    #pragma unroll 1
    for (int rg = 0; rg < 4; ++rg) {
        const int ql = wv * 16 + rg * 4 + rg4;
        int q = qb + ql; if (q > HW - 1) q = HW - 1;
        const float* rowA = c4A + ((size_t)b * HW + q) * HW;
        const float* rowB = c4B + ((size_t)b * HW + q) * HW;
        float4 v4[7];
        #pragma unroll
        for (int k4 = 0; k4 < 6; ++k4) {
            float4 a4 = *(const float4*)(rowA + 64 * k4 + lane16 * 4);
            float4 b4 = *(const float4*)(rowB + 64 * k4 + lane16 * 4);
            v4[k4] = make_float4(a4.x + b4.x, a4.y + b4.y, a4.z + b4.z, a4.w + b4.w);
        }
        if (lane16 < 4) {
            float4 a4 = *(const float4*)(rowA + 384 + lane16 * 4);
            float4 b4 = *(const float4*)(rowB + 384 + lane16 * 4);
            v4[6] = make_float4(a4.x + b4.x, a4.y + b4.y, a4.z + b4.z, a4.w + b4.w);
        } else {
            v4[6] = make_float4(-1e30f, -1e30f, -1e30f, -1e30f);
        }
        float mx = -1e30f;
        #pragma unroll
        for (int k4 = 0; k4 < 7; ++k4)
            mx = fmaxf(mx, fmaxf(fmaxf(v4[k4].x, v4[k4].y), fmaxf(v4[k4].z, v4[k4].w)));
        #pragma unroll
        for (int off = 8; off; off >>= 1) mx = fmaxf(mx, __shfl_xor(mx, off, 16));
        float sum = 0.f;
        #pragma unroll
        for (int k4 = 0; k4 < 7; ++k4) {
            if (k4 == 6 && lane16 >= 4) break;
            float e0 = __expf(TEMPF * (v4[k4].x - mx));
            float e1 = __expf(TEMPF * (v4[k4].y - mx));
            float e2 = __expf(TEMPF * (v4[k4].z - mx));
            float e3 = __expf(TEMPF * (v4[k4].w - mx));
            sum += e0 + e1 + e2 + e3;
            union { ushort_t us[4]; uint2 u2; } pk;
            union { _Float16 h; ushort_t u16; } cv;
            cv.h = (_Float16)e0; pk.us[0] = cv.u16;
            cv.h = (_Float16)e1; pk.us[1] = cv.u16;
            cv.h = (_Float16)e2; pk.us[2] = cv.u16;
            cv.h = (_Float16)e3; pk.us[3] = cv.u16;
            *(uint2*)&P[(size_t)ql * 424 + 64 * k4 + lane16 * 4] = pk.u2;
        }
        if (lane16 >= 4 && lane16 < 10) {
            uint2 z2; z2.x = 0; z2.y = 0;
            *(uint2*)&P[(size_t)ql * 424 + 384 + lane16 * 4] = z2;
        }
        #pragma unroll
        for (int off = 8; off; off >>= 1) sum += __shfl_xor(sum, off, 16);
        if (lane16 == 0) invl[ql] = 1.0f / sum;
    }

    // ---- phase 2: AV GEMM for this wave's 16 rows x 2 nt tiles ----
    half8 afr[13];
    #pragma unroll
    for (int ks = 0; ks < 13; ++ks)
        afr[ks] = *(const half8*)&P[(size_t)(wv * 16 + m16) * 424 + ks * 32 + q4 * 8];
    const ushort_t* fb = fsh + (size_t)b * CH * 416;
    #pragma unroll
    for (int ntl = 0; ntl < 2; ++ntl) {
        const int nt = blockIdx.y * 2 + ntl;
        const int c = nt * 16 + m16;
        const ushort_t* fc = fb + (size_t)c * 416 + q4 * 8;
        f32x4 acc = {};
        #pragma unroll
        for (int ks = 0; ks < 13; ++ks) {
            half8 bf = *(const half8*)(fc + ks * 32);
            acc = __builtin_amdgcn_mfma_f32_16x16x32_f16(afr[ks], bf, acc, 0, 0, 0);
        }
        #pragma unroll
        for (int r = 0; r < 4; ++r) {
            int ql = wv * 16 + q4 * 4 + r;
            int q = qb + ql;
            if (q < HW)
                att[((size_t)b * CH + c) * HW + q] = acc[r] * invl[ql];
        }
    }
}

// ---------------------------------------------------------------------------
// Kernel 6: fq = l2norm(f_q, ch) + 0.5 * l2norm(att_fq, ch)
// ---------------------------------------------------------------------------
__global__ __launch_bounds__(256) void final_fq(const float* __restrict__ f_q,
                                                const float* __restrict__ att,
                                                float* __restrict__ out_fq) {
    __shared__ float red[256];
    int b = blockIdx.y, q = blockIdx.x;
    int tid = threadIdx.x;
    size_t idx = (size_t)(b * CH + tid) * HW + q;
    float f = f_q[idx];
    float a = att[idx];
    red[tid] = f * f;
    __syncthreads();
    for (int s = 128; s > 0; s >>= 1) {
        if (tid < s) red[tid] += red[tid + s];
        __syncthreads();
    }
    float invf = 1.0f / fmaxf(sqrtf(red[0]), EPSF);
    __syncthreads();
    red[tid] = a * a;
    __syncthreads();
    for (int s = 128; s > 0; s >>= 1) {
        if (tid < s) red[tid] += red[tid + s];
        __syncthreads();
    }
    float inva = 1.0f / fmaxf(sqrtf(red[0]), EPSF);
    out_fq[idx] = f * invf + 0.5f * a * inva;
}

// ---------------------------------------------------------------------------
extern "C" void kernel_launch(void* const* d_in, const int* in_sizes, int n_in,
                              void* d_out, int out_size, void* d_ws, size_t ws_size,
                              hipStream_t stream) {
    const float* fq_feats = (const float*)d_in[0];
    const float* fs_feats = (const float*)d_in[1];
    const float* f_q      = (const float*)d_in[2];
    const float* f_s      = (const float*)d_in[3];
    const float* w1       = (const float*)d_in[4];
    const float* w2       = (const float*)d_in[5];
    const float* w3       = (const float*)d_in[6];
    float* out = (float*)d_out;              // fq at 0, att_fq at 204800

    float* ws      = (float*)d_ws;
    float* wbuf    = ws;                     // 115,200 fl: weight tables
    float* invn    = wbuf + 115200;          // 14,400
    float* corr    = invn + 14400;           // 2,880,000 fl region:
                                             //   [0 .. 1.44M) corr f16
                                             //   [1.44M .. 1.55M) fsh f16
                                             //   [1.60M .. 1.92M) c4A f32
                                             //   [1.92M .. 2.24M) c4B f32
    float* buf1    = corr + 2880000;         // 3,200,000 (partial2 / At / b1A+b1B)
    float* buf2    = buf1 + 3200000;         // 3,200,000 (Bt / b2A+b2B)
    float* att     = out + 204800;

    float* partial2 = buf1;
    ushort_t* corr_h = (ushort_t*)corr;
    ushort_t* fsh    = (ushort_t*)(corr + 1440000);
    float* c4A = corr + 1600000;
    float* c4B = corr + 1920000;
    ushort_t* At = (ushort_t*)buf1;
    ushort_t* Bt = (ushort_t*)buf2;
    ushort_t* b1A = (ushort_t*)buf1;
    ushort_t* b1B = b1A + 3200000;
    ushort_t* b2A = (ushort_t*)buf2;
    ushort_t* b2B = b2A + 3200000;

    ushort_t* wb0   = (ushort_t*)wbuf;
    ushort_t* wbL1A = wb0;
    ushort_t* wbL1B = wb0 + 13824;
    ushort_t* wbL2A = wb0 + 27648;
    ushort_t* wbL2B = wb0 + 41472;
    ushort_t* wbL3A = wb0 + 55296;
    ushort_t* wbL3B = wb0 + 69120;

    norm_partial2<<<dim3(16, 18, 2), 256, 0, stream>>>(fq_feats, fs_feats, partial2);
    norm_finalize2<<<(2 * 18 * HW + 255) / 256, 256, 0, stream>>>(partial2, invn);

    wprep7<9, 10, false><<<54, 256, 0, stream>>>(w1, wbL1A);
    wprep7<9, 10, true ><<<54, 256, 0, stream>>>(w1, wbL1B);
    wprep7<10, 10, false><<<54, 256, 0, stream>>>(w2, wbL2A);
    wprep7<10, 10, true ><<<54, 256, 0, stream>>>(w2, wbL2B);
    wprep7<10, 1, false><<<54, 256, 0, stream>>>(w3, wbL3A);
    wprep7<10, 1, true ><<<54, 256, 0, stream>>>(w3, wbL3B);
    fs_prep<<<(NB * CH * 416 + 255) / 256, 256, 0, stream>>>(f_s, fsh);

    for (int half = 0; half < 2; ++half) {
        int base = half * 9;
        transpose_f16<<<dim3(16, 7, 18), 256, 0, stream>>>(fq_feats, fs_feats, At, Bt, base);
        corr_gemm_mfma<<<dim3(7, 7, 9), 256, 0, stream>>>(At, Bt, invn, corr_h, base);
    }

    // L1: both paths, one staging (DUAL), 800 blocks
    conv4d_v8<9, 10, true, true><<<dim3(400, NB, 1), 256, 0, stream>>>(
        corr_h, corr_h, wbL1A, wbL1B, b1A, b1B);
    // L2: paths merged via grid-z, 1600 blocks
    conv4d_v8<10, 10, false, true><<<dim3(400, NB, 2), 256, 0, stream>>>(
        b1A, b1B, wbL2A, wbL2B, b2A, b2B);
    // L3: paths merged via grid-z, disjoint f32 outputs, 1600 blocks
    conv4d_v8<10, 1, false, false><<<dim3(400, NB, 2), 256, 0, stream>>>(
        b2A, b2B, wbL3A, wbL3B, c4A, c4B);

    softmax_av_mfma2<<<dim3(7, 8, NB), 256, 0, stream>>>(c4A, c4B, fsh, att);
    final_fq<<<dim3(400, NB), 256, 0, stream>>>(f_q, att, out);

    (void)in_sizes; (void)n_in; (void)out_size; (void)ws_size;
}